// Round 1
// 170.650 us; speedup vs baseline: 1.1465x; 1.1465x over previous
//
#include <hip/hip_runtime.h>

#define CDIM 128
#define NHEADS 8
#define HD 16
#define NTOK 64
#define HW 65536          // 256*256 pixels per image
#define XSTR 136          // padded row stride (bf16 shorts) for 64x128 tiles
#define VSTR 72           // padded row stride for [16][64] scratch tiles

typedef short s8v __attribute__((ext_vector_type(8)));
typedef short s4v __attribute__((ext_vector_type(4)));
typedef float f4v __attribute__((ext_vector_type(4)));

static __device__ __forceinline__ short f2bf(float f) {
    unsigned u = __float_as_uint(f);
    u += 0x7FFFu + ((u >> 16) & 1u);   // RNE
    return (short)(u >> 16);
}

// ---- Prologue 1: pack qkv_w (rows 0..383) + proj_w (rows 0..127) into MFMA
// fragment order. frag f = ob*4+kc; ob 0..7 = q (pre-scaled 0.25), 8..15 = k,
// 16..23 = v, 24..31 = proj.  wpk[(f*64+lane)*8 + j] =
//   W[ob*16 + (lane&15)][kc*32 + (lane>>4)*8 + j]
__global__ __launch_bounds__(256) void pack_w_kernel(
    const float* __restrict__ qkv_w, const float* __restrict__ proj_w,
    short* __restrict__ wpk)
{
    int idx = blockIdx.x * 256 + threadIdx.x;   // 0..8191
    int lane = idx & 63, kc = (idx >> 6) & 3, ob = idx >> 8;
    int row = (ob < 24) ? ob * 16 + (lane & 15) : (ob - 24) * 16 + (lane & 15);
    int col = kc * 32 + (lane >> 4) * 8;
    const float* src = ((ob < 24) ? qkv_w : proj_w) + (size_t)row * CDIM + col;
    float sc = (ob < 8) ? 0.25f : 1.0f;
    float4 f0 = *(const float4*)src;
    float4 f1 = *(const float4*)(src + 4);
    s8v r;
    r[0] = f2bf(f0.x * sc); r[1] = f2bf(f0.y * sc);
    r[2] = f2bf(f0.z * sc); r[3] = f2bf(f0.w * sc);
    r[4] = f2bf(f1.x * sc); r[5] = f2bf(f1.y * sc);
    r[6] = f2bf(f1.z * sc); r[7] = f2bf(f1.w * sc);
    *(s8v*)&wpk[(size_t)idx * 8] = r;
}

// ---- Prologue 2: gather rel_bias[rel_index] into S^T C-fragment order:
// biasf[(((h*4+mq)*4+nt)*64 + lane)*4 + r] =
//   bias[h][t_q = mq*16+(lane&15)][t_k = nt*16+(lane>>4)*4+r]
// (transposed vs the plain-S layout: lane column = QUERY token now)
__global__ __launch_bounds__(256) void pack_b_kernel(
    const float* __restrict__ rel_bias, const int* __restrict__ rel_index,
    float* __restrict__ biasf)
{
    int idx = blockIdx.x * 256 + threadIdx.x;   // 0..8191
    int lane = idx & 63, nt = (idx >> 6) & 3, mq = (idx >> 8) & 3, h = idx >> 10;
    int tq  = mq * 16 + (lane & 15);
    int tk0 = nt * 16 + (lane >> 4) * 4;
    f4v v;
    #pragma unroll
    for (int r = 0; r < 4; ++r)
        v[r] = rel_bias[rel_index[tq * 64 + tk0 + r] * NHEADS + h];
    *(f4v*)&biasf[(size_t)idx * 4] = v;
}

// ---- Main: one block per 8x8 window, 256 threads = 4 waves.
// Wave wv owns heads {wv, wv+4}: it computes q/k/v for those heads in the
// QKV GEMM and consumes them itself in attention -> no barrier between the
// QKV GEMM and attention. LDS = 53248 B -> 3 blocks/CU (was 79872 -> 2).
__global__ __launch_bounds__(256, 3) void winattn_kernel(
    const float* __restrict__ x, const float* __restrict__ qkv_b,
    const float* __restrict__ proj_b, const short* __restrict__ wpk,
    const float* __restrict__ biasf, float* __restrict__ out)
{
    // xs: staged x (granule-swizzled) -> overlaid by q -> overlaid by attn-out
    __shared__ __align__(16) short xs[NTOK * XSTR];        // 17408 B
    __shared__ __align__(16) short ks[NTOK * XSTR];        // 17408 B (k [t][o])
    __shared__ __align__(16) short vsc[4 * 2 * 16 * VSTR]; // 18432 B scratch

    const int tid  = threadIdx.x;
    const int lane = tid & 63;
    const int wv   = tid >> 6;
    const int qd   = lane >> 4;
    const int l15  = lane & 15;

    // XCD swizzle: consecutive logical windows -> same XCD (L2 line sharing)
    const int wid = (blockIdx.x & 7) * 256 + (blockIdx.x >> 3);
    const int b   = wid >> 10;
    const int wy  = (wid >> 5) & 31, wx = wid & 31;
    const int h0  = wy * 8, w0 = wx * 8;
    const float* xb = x + (size_t)b * CDIM * HW;

    // ---------- Stage 1: stage x window into xs (bf16, granule-swizzled) ----
    // Layout: element (t, c) lives at xs[t*XSTR + (((c>>3) ^ ((t>>2)&7))<<3) + (c&7)].
    // Lane remap (c from lane&7, tq from lane>>3) + swizzle makes the columnar
    // b16 writes <=2-way bank conflicted (was 8-way).
    #pragma unroll
    for (int it = 0; it < 8; ++it) {
        const int g   = it * 4 + wv;              // 0..31 group id
        const int cg  = g & 15, tqg = g >> 4;
        const int c   = cg * 8 + (lane & 7);
        const int tq  = tqg * 8 + ((lane >> 3) & 7);
        const int t0  = tq * 4;
        float4 f = *(const float4*)&xb[(size_t)c * HW + (h0 + (t0 >> 3)) * 256 + w0 + (t0 & 7)];
        const int col = ((cg ^ (tq & 7)) << 3) | (c & 7);
        xs[(t0 + 0) * XSTR + col] = f2bf(f.x);
        xs[(t0 + 1) * XSTR + col] = f2bf(f.y);
        xs[(t0 + 2) * XSTR + col] = f2bf(f.z);
        xs[(t0 + 3) * XSTR + col] = f2bf(f.w);
    }
    __syncthreads();

    // ---------- Stage 2: QKV GEMM, head-aligned per wave ----------
    s8v vf[2][2];   // v B-frags for heads {wv, wv+4}, kc = 0,1 (16 VGPRs)
    {
        // X A-frags: X[tb][kc] = x[t = tb*16+l15][c = kc*32+qd*8 .. +7] (swizzled read)
        s8v X[4][4];
        #pragma unroll
        for (int tb = 0; tb < 4; ++tb)
            #pragma unroll
            for (int kc = 0; kc < 4; ++kc) {
                const int gr = ((4 * kc + qd) ^ ((4 * tb + (l15 >> 2)) & 7)) << 3;
                X[tb][kc] = *(const s8v*)&xs[(tb * 16 + l15) * XSTR + gr];
            }

        const s8v* wf = (const s8v*)wpk;

        // --- k for own heads: D[o][t] = mfma(Wk, X), write ks[t][o] (b64 rows)
        #pragma unroll
        for (int hp = 0; hp < 2; ++hp) {
            const int h = wv + hp * 4;
            const int ob = 8 + h;
            s8v W[4];
            #pragma unroll
            for (int kc = 0; kc < 4; ++kc) W[kc] = wf[(ob * 4 + kc) * 64 + lane];
            float4 kb = *(const float4*)&qkv_b[128 + h * 16 + qd * 4];
            float kbr[4] = {kb.x, kb.y, kb.z, kb.w};
            #pragma unroll
            for (int tb = 0; tb < 4; ++tb) {
                f4v acc = {0.f, 0.f, 0.f, 0.f};
                #pragma unroll
                for (int kc = 0; kc < 4; ++kc)
                    acc = __builtin_amdgcn_mfma_f32_16x16x32_bf16(W[kc], X[tb][kc], acc, 0, 0, 0);
                s4v pk;
                #pragma unroll
                for (int r = 0; r < 4; ++r) pk[r] = f2bf(acc[r] + kbr[r]);
                *(s4v*)&ks[(tb * 16 + l15) * XSTR + h * 16 + qd * 4] = pk;
            }
        }

        // --- v for own heads: D[t][o] = mfma(X, Wv) -> per-wave scratch [o][t]
        //     -> read back as PV B-frags into registers (same wave, no barrier)
        #pragma unroll
        for (int hp = 0; hp < 2; ++hp) {
            const int h = wv + hp * 4;
            const int ob = 16 + h;
            short* vw = &vsc[(wv * 2 + hp) * 16 * VSTR];
            s8v W[4];
            #pragma unroll
            for (int kc = 0; kc < 4; ++kc) W[kc] = wf[(ob * 4 + kc) * 64 + lane];
            const float vb = qkv_b[256 + h * 16 + l15];
            #pragma unroll
            for (int tb = 0; tb < 4; ++tb) {
                f4v acc = {0.f, 0.f, 0.f, 0.f};
                #pragma unroll
                for (int kc = 0; kc < 4; ++kc)
                    acc = __builtin_amdgcn_mfma_f32_16x16x32_bf16(X[tb][kc], W[kc], acc, 0, 0, 0);
                s4v pk;
                #pragma unroll
                for (int r = 0; r < 4; ++r) pk[r] = f2bf(acc[r] + vb);
                *(s4v*)&vw[l15 * VSTR + tb * 16 + qd * 4] = pk;
            }
            vf[hp][0] = *(const s8v*)&vw[l15 * VSTR + qd * 8];
            vf[hp][1] = *(const s8v*)&vw[l15 * VSTR + 32 + qd * 8];
        }

        // All waves must be done READING xs (X frags loaded above) before any
        // wave overwrites it with q.
        __syncthreads();

        // --- q for own heads: D[o][t] = mfma(Wq, X), write into xs overlay
        //     (plain, unswizzled addressing; head-column slices are wave-private)
        #pragma unroll
        for (int hp = 0; hp < 2; ++hp) {
            const int h = wv + hp * 4;
            const int ob = h;
            s8v W[4];
            #pragma unroll
            for (int kc = 0; kc < 4; ++kc) W[kc] = wf[(ob * 4 + kc) * 64 + lane];
            float4 qb = *(const float4*)&qkv_b[h * 16 + qd * 4];
            float qbr[4] = {qb.x * 0.25f, qb.y * 0.25f, qb.z * 0.25f, qb.w * 0.25f};
            #pragma unroll
            for (int tb = 0; tb < 4; ++tb) {
                f4v acc = {0.f, 0.f, 0.f, 0.f};
                #pragma unroll
                for (int kc = 0; kc < 4; ++kc)
                    acc = __builtin_amdgcn_mfma_f32_16x16x32_bf16(W[kc], X[tb][kc], acc, 0, 0, 0);
                s4v pk;
                #pragma unroll
                for (int r = 0; r < 4; ++r) pk[r] = f2bf(acc[r] + qbr[r]);
                *(s4v*)&xs[(tb * 16 + l15) * XSTR + h * 16 + qd * 4] = pk;
            }
        }
    }

    // ---------- Stage 3: attention (no barrier needed: all same-wave) -------
    // S^T trick: compute S^T[t_k][t_q] = mfma(k, q). Lane then holds 16 score
    // values for ONE query token (col = l15) -> softmax reduction is a
    // lane-local tree + 2 shfl_xor (across qd), and normalization folds into P.
    short* os = xs;   // attention-out overlays q slices head-by-head
    const s8v z8 = {};
    #pragma unroll
    for (int hp = 0; hp < 2; ++hp) {
        const int h = wv + hp * 4;
        s8v kf[4];    // A-frags: k[t_k = nt*16+l15][c]  (c>=16 lanes zeroed)
        #pragma unroll
        for (int nt = 0; nt < 4; ++nt) {
            s8v kr = *(const s8v*)&ks[(nt * 16 + l15) * XSTR + h * 16 + (qd & 1) * 8];
            kf[nt] = (qd < 2) ? kr : z8;
        }
        #pragma unroll
        for (int mq = 0; mq < 4; ++mq) {
            // q B-frag: q[t_q = mq*16+l15][c] (upper-c garbage x kf zeros = 0)
            s8v qf = *(const s8v*)&xs[(mq * 16 + l15) * XSTR + h * 16 + (qd & 1) * 8];
            f4v sv[4];
            #pragma unroll
            for (int nt = 0; nt < 4; ++nt) {
                f4v s = {0.f, 0.f, 0.f, 0.f};
                s = __builtin_amdgcn_mfma_f32_16x16x32_bf16(kf[nt], qf, s, 0, 0, 0);
                f4v bf = *(const f4v*)&biasf[(size_t)(((h * 4 + mq) * 4 + nt) * 64 + lane) * 4];
                sv[nt] = s + bf;   // scale folded into q
            }
            // softmax over t_k (rows of S^T): lane-local 16 + 2 shfl across qd
            f4v a;
            #pragma unroll
            for (int r = 0; r < 4; ++r)
                a[r] = fmaxf(fmaxf(sv[0][r], sv[1][r]), fmaxf(sv[2][r], sv[3][r]));
            float mx = fmaxf(fmaxf(a[0], a[1]), fmaxf(a[2], a[3]));
            mx = fmaxf(mx, __shfl_xor(mx, 16, 64));
            mx = fmaxf(mx, __shfl_xor(mx, 32, 64));
            float sm = 0.f;
            #pragma unroll
            for (int nt = 0; nt < 4; ++nt)
                #pragma unroll
                for (int r = 0; r < 4; ++r) { sv[nt][r] = __expf(sv[nt][r] - mx); sm += sv[nt][r]; }
            sm += __shfl_xor(sm, 16, 64);
            sm += __shfl_xor(sm, 32, 64);
            const float inv = 1.f / sm;
            // normalized P -> scratch [t_q][t_k] with ROW-contiguous b64 writes
            short* pw = &vsc[(wv * 2 + (mq & 1)) * 16 * VSTR];
            #pragma unroll
            for (int nt = 0; nt < 4; ++nt) {
                s4v pk;
                #pragma unroll
                for (int r = 0; r < 4; ++r) pk[r] = f2bf(sv[nt][r] * inv);
                *(s4v*)&pw[l15 * VSTR + nt * 16 + qd * 4] = pk;
            }
            s8v pa0 = *(const s8v*)&pw[l15 * VSTR + qd * 8];
            s8v pa1 = *(const s8v*)&pw[l15 * VSTR + 32 + qd * 8];
            f4v O = {0.f, 0.f, 0.f, 0.f};
            O = __builtin_amdgcn_mfma_f32_16x16x32_bf16(pa0, vf[hp][0], O, 0, 0, 0);
            O = __builtin_amdgcn_mfma_f32_16x16x32_bf16(pa1, vf[hp][1], O, 0, 0, 0);
            #pragma unroll
            for (int r = 0; r < 4; ++r)
                os[(mq * 16 + qd * 4 + r) * XSTR + h * HD + l15] = f2bf(O[r]);
        }
    }
    __syncthreads();

    // ---------- Stage 4: fused proj from prepacked fragments ----------
    {
        s8v A[4][4];
        #pragma unroll
        for (int mt = 0; mt < 4; ++mt)
            #pragma unroll
            for (int kc = 0; kc < 4; ++kc)
                A[mt][kc] = *(const s8v*)&os[(mt * 16 + l15) * XSTR + kc * 32 + qd * 8];

        const s8v* wf = (const s8v*)wpk;
        s8v B[2][4];
        float pb2[2]; int o2[2];
        #pragma unroll
        for (int nt = 0; nt < 2; ++nt) {
            const int ob = 24 + wv * 2 + nt;
            o2[nt] = (wv * 2 + nt) * 16 + l15;
            pb2[nt] = proj_b[o2[nt]];
            #pragma unroll
            for (int kc = 0; kc < 4; ++kc) B[nt][kc] = wf[(ob * 4 + kc) * 64 + lane];
        }
        #pragma unroll
        for (int mt = 0; mt < 4; ++mt) {
            const int t0 = mt * 16 + qd * 4;
            const int pix = (h0 + (t0 >> 3)) * 256 + w0 + (t0 & 7);
            #pragma unroll
            for (int nt = 0; nt < 2; ++nt) {
                f4v acc = {0.f, 0.f, 0.f, 0.f};
                #pragma unroll
                for (int kc = 0; kc < 4; ++kc)
                    acc = __builtin_amdgcn_mfma_f32_16x16x32_bf16(A[mt][kc], B[nt][kc], acc, 0, 0, 0);
                float4 v = make_float4(acc[0] + pb2[nt], acc[1] + pb2[nt],
                                       acc[2] + pb2[nt], acc[3] + pb2[nt]);
                *(float4*)&out[((size_t)(b * CDIM + o2[nt])) * HW + pix] = v;
            }
        }
    }
}

extern "C" void kernel_launch(void* const* d_in, const int* in_sizes, int n_in,
                              void* d_out, int out_size, void* d_ws, size_t ws_size,
                              hipStream_t stream) {
    const float* x        = (const float*)d_in[0];
    const float* qkv_w    = (const float*)d_in[1];
    const float* qkv_b    = (const float*)d_in[2];
    const float* proj_w   = (const float*)d_in[3];
    const float* proj_b   = (const float*)d_in[4];
    const float* rel_bias = (const float*)d_in[5];
    const int*   rel_index= (const int*)d_in[6];
    float* out = (float*)d_out;

    short* wpk   = (short*)d_ws;                       // 32*4*64*8 shorts = 128 KB
    float* biasf = (float*)((char*)d_ws + 131072);     // 8192 float4 = 128 KB

    pack_w_kernel<<<32, 256, 0, stream>>>(qkv_w, proj_w, wpk);
    pack_b_kernel<<<32, 256, 0, stream>>>(rel_bias, rel_index, biasf);
    winattn_kernel<<<2048, 256, 0, stream>>>(x, qkv_b, proj_b, wpk, biasf, out);
}

// Round 2
// 168.661 us; speedup vs baseline: 1.1600x; 1.0118x over previous
//
#include <hip/hip_runtime.h>

#define CDIM 128
#define NHEADS 8
#define HD 16
#define NTOK 64
#define HW 65536          // 256*256 pixels per image
#define XSTR 136          // padded row stride (bf16 shorts) for 64x128 tiles
#define VSTR 72           // padded row stride for [16][64] scratch tiles
#define LOG2E 1.44269504088896f

typedef short s8v __attribute__((ext_vector_type(8)));
typedef short s4v __attribute__((ext_vector_type(4)));
typedef float f4v __attribute__((ext_vector_type(4)));

static __device__ __forceinline__ short f2bf(float f) {
    unsigned u = __float_as_uint(f);
    u += 0x7FFFu + ((u >> 16) & 1u);   // RNE
    return (short)(u >> 16);
}

// ---- Prologue 1: pack qkv_w (rows 0..383) + proj_w (rows 0..127) into MFMA
// fragment order. frag f = ob*4+kc; ob 0..7 = q (pre-scaled 0.25*log2e so the
// softmax can use exp2 directly), 8..15 = k, 16..23 = v, 24..31 = proj.
// wpk[(f*64+lane)*8 + j] = W[ob*16 + (lane&15)][kc*32 + (lane>>4)*8 + j]
__global__ __launch_bounds__(256) void pack_w_kernel(
    const float* __restrict__ qkv_w, const float* __restrict__ proj_w,
    short* __restrict__ wpk)
{
    int idx = blockIdx.x * 256 + threadIdx.x;   // 0..8191
    int lane = idx & 63, kc = (idx >> 6) & 3, ob = idx >> 8;
    int row = (ob < 24) ? ob * 16 + (lane & 15) : (ob - 24) * 16 + (lane & 15);
    int col = kc * 32 + (lane >> 4) * 8;
    const float* src = ((ob < 24) ? qkv_w : proj_w) + (size_t)row * CDIM + col;
    float sc = (ob < 8) ? 0.25f * LOG2E : 1.0f;
    float4 f0 = *(const float4*)src;
    float4 f1 = *(const float4*)(src + 4);
    s8v r;
    r[0] = f2bf(f0.x * sc); r[1] = f2bf(f0.y * sc);
    r[2] = f2bf(f0.z * sc); r[3] = f2bf(f0.w * sc);
    r[4] = f2bf(f1.x * sc); r[5] = f2bf(f1.y * sc);
    r[6] = f2bf(f1.z * sc); r[7] = f2bf(f1.w * sc);
    *(s8v*)&wpk[(size_t)idx * 8] = r;
}

// ---- Prologue 2: gather rel_bias[rel_index] (scaled by log2e) into S^T
// C-fragment order: biasf[(((h*4+mq)*4+nt)*64 + lane)*4 + r] =
//   log2e * bias[h][t_q = mq*16+(lane&15)][t_k = nt*16+(lane>>4)*4+r]
__global__ __launch_bounds__(256) void pack_b_kernel(
    const float* __restrict__ rel_bias, const int* __restrict__ rel_index,
    float* __restrict__ biasf)
{
    int idx = blockIdx.x * 256 + threadIdx.x;   // 0..8191
    int lane = idx & 63, nt = (idx >> 6) & 3, mq = (idx >> 8) & 3, h = idx >> 10;
    int tq  = mq * 16 + (lane & 15);
    int tk0 = nt * 16 + (lane >> 4) * 4;
    f4v v;
    #pragma unroll
    for (int r = 0; r < 4; ++r)
        v[r] = LOG2E * rel_bias[rel_index[tq * 64 + tk0 + r] * NHEADS + h];
    *(f4v*)&biasf[(size_t)idx * 4] = v;
}

// ---- Main: one block per 8x8 window, 256 threads = 4 waves.
// Wave wv owns heads {wv, wv+4}. Stage 3 runs both head chains interleaved
// (mq outer) so the two serial softmax chains overlap.
__global__ __launch_bounds__(256, 3) void winattn_kernel(
    const float* __restrict__ x, const float* __restrict__ qkv_b,
    const float* __restrict__ proj_b, const short* __restrict__ wpk,
    const float* __restrict__ biasf, float* __restrict__ out)
{
    // xs: staged x (granule-swizzled) -> overlaid by q -> overlaid by attn-out
    __shared__ __align__(16) short xs[NTOK * XSTR];        // 17408 B
    __shared__ __align__(16) short ks[NTOK * XSTR];        // 17408 B (k [t][o])
    __shared__ __align__(16) short vsc[4 * 2 * 16 * VSTR]; // 18432 B scratch

    const int tid  = threadIdx.x;
    const int lane = tid & 63;
    const int wv   = tid >> 6;
    const int qd   = lane >> 4;
    const int l15  = lane & 15;

    // XCD swizzle: consecutive logical windows -> same XCD (L2 line sharing)
    const int wid = (blockIdx.x & 7) * 256 + (blockIdx.x >> 3);
    const int b   = wid >> 10;
    const int wy  = (wid >> 5) & 31, wx = wid & 31;
    const int h0  = wy * 8, w0 = wx * 8;
    const float* xb = x + (size_t)b * CDIM * HW;

    // ---------- Stage 1: stage x window into xs (bf16, granule-swizzled) ----
    // Element (t, c) lives at xs[t*XSTR + (((c>>3) ^ ((t>>2)&7))<<3) + (c&7)].
    #pragma unroll
    for (int it = 0; it < 8; ++it) {
        const int g   = it * 4 + wv;              // 0..31 group id
        const int cg  = g & 15, tqg = g >> 4;
        const int c   = cg * 8 + (lane & 7);
        const int tq  = tqg * 8 + ((lane >> 3) & 7);
        const int t0  = tq * 4;
        float4 f = *(const float4*)&xb[(size_t)c * HW + (h0 + (t0 >> 3)) * 256 + w0 + (t0 & 7)];
        const int col = ((cg ^ (tq & 7)) << 3) | (c & 7);
        xs[(t0 + 0) * XSTR + col] = f2bf(f.x);
        xs[(t0 + 1) * XSTR + col] = f2bf(f.y);
        xs[(t0 + 2) * XSTR + col] = f2bf(f.z);
        xs[(t0 + 3) * XSTR + col] = f2bf(f.w);
    }
    __syncthreads();

    // ---------- Stage 2: QKV GEMM, head-aligned per wave ----------
    s8v vf[2][2];   // v B-frags for heads {wv, wv+4}, kc = 0,1
    {
        // X A-frags: X[tb][kc] = x[t = tb*16+l15][c = kc*32+qd*8 .. +7]
        s8v X[4][4];
        #pragma unroll
        for (int tb = 0; tb < 4; ++tb)
            #pragma unroll
            for (int kc = 0; kc < 4; ++kc) {
                const int gr = ((4 * kc + qd) ^ ((4 * tb + (l15 >> 2)) & 7)) << 3;
                X[tb][kc] = *(const s8v*)&xs[(tb * 16 + l15) * XSTR + gr];
            }

        const s8v* wf = (const s8v*)wpk;

        // --- k for own heads: hoist W for both heads, then compute.
        {
            s8v Wk[2][4];
            #pragma unroll
            for (int hp = 0; hp < 2; ++hp) {
                const int ob = 8 + wv + hp * 4;
                #pragma unroll
                for (int kc = 0; kc < 4; ++kc) Wk[hp][kc] = wf[(ob * 4 + kc) * 64 + lane];
            }
            #pragma unroll
            for (int hp = 0; hp < 2; ++hp) {
                const int h = wv + hp * 4;
                float4 kb = *(const float4*)&qkv_b[128 + h * 16 + qd * 4];
                float kbr[4] = {kb.x, kb.y, kb.z, kb.w};
                #pragma unroll
                for (int tb = 0; tb < 4; ++tb) {
                    f4v acc = {0.f, 0.f, 0.f, 0.f};
                    #pragma unroll
                    for (int kc = 0; kc < 4; ++kc)
                        acc = __builtin_amdgcn_mfma_f32_16x16x32_bf16(Wk[hp][kc], X[tb][kc], acc, 0, 0, 0);
                    s4v pk;
                    #pragma unroll
                    for (int r = 0; r < 4; ++r) pk[r] = f2bf(acc[r] + kbr[r]);
                    *(s4v*)&ks[(tb * 16 + l15) * XSTR + h * 16 + qd * 4] = pk;
                }
            }
        }

        // --- v for own heads -> per-wave scratch [o][t] -> vf regs
        {
            s8v Wv[2][4];
            #pragma unroll
            for (int hp = 0; hp < 2; ++hp) {
                const int ob = 16 + wv + hp * 4;
                #pragma unroll
                for (int kc = 0; kc < 4; ++kc) Wv[hp][kc] = wf[(ob * 4 + kc) * 64 + lane];
            }
            #pragma unroll
            for (int hp = 0; hp < 2; ++hp) {
                const int h = wv + hp * 4;
                short* vw = &vsc[(wv * 2 + hp) * 16 * VSTR];
                const float vb = qkv_b[256 + h * 16 + l15];
                #pragma unroll
                for (int tb = 0; tb < 4; ++tb) {
                    f4v acc = {0.f, 0.f, 0.f, 0.f};
                    #pragma unroll
                    for (int kc = 0; kc < 4; ++kc)
                        acc = __builtin_amdgcn_mfma_f32_16x16x32_bf16(X[tb][kc], Wv[hp][kc], acc, 0, 0, 0);
                    s4v pk;
                    #pragma unroll
                    for (int r = 0; r < 4; ++r) pk[r] = f2bf(acc[r] + vb);
                    *(s4v*)&vw[l15 * VSTR + tb * 16 + qd * 4] = pk;
                }
                vf[hp][0] = *(const s8v*)&vw[l15 * VSTR + qd * 8];
                vf[hp][1] = *(const s8v*)&vw[l15 * VSTR + 32 + qd * 8];
            }
        }

        // --- q: issue W loads BEFORE the barrier (latency overlaps the wait).
        s8v Wq[2][4];
        #pragma unroll
        for (int hp = 0; hp < 2; ++hp) {
            const int ob = wv + hp * 4;
            #pragma unroll
            for (int kc = 0; kc < 4; ++kc) Wq[hp][kc] = wf[(ob * 4 + kc) * 64 + lane];
        }

        // All waves must be done READING xs before q overlays it.
        __syncthreads();

        #pragma unroll
        for (int hp = 0; hp < 2; ++hp) {
            const int h = wv + hp * 4;
            float4 qb = *(const float4*)&qkv_b[h * 16 + qd * 4];
            const float qsc = 0.25f * LOG2E;
            float qbr[4] = {qb.x * qsc, qb.y * qsc, qb.z * qsc, qb.w * qsc};
            #pragma unroll
            for (int tb = 0; tb < 4; ++tb) {
                f4v acc = {0.f, 0.f, 0.f, 0.f};
                #pragma unroll
                for (int kc = 0; kc < 4; ++kc)
                    acc = __builtin_amdgcn_mfma_f32_16x16x32_bf16(Wq[hp][kc], X[tb][kc], acc, 0, 0, 0);
                s4v pk;
                #pragma unroll
                for (int r = 0; r < 4; ++r) pk[r] = f2bf(acc[r] + qbr[r]);
                *(s4v*)&xs[(tb * 16 + l15) * XSTR + h * 16 + qd * 4] = pk;
            }
        }
    }

    // ---------- Stage 3: attention, both head chains interleaved ----------
    // S^T[t_k][t_q] = mfma(k, q): lane holds 16 scores of ONE query (col=l15);
    // softmax = lane-local tree + 2 shfl across qd. Both hp chains run side by
    // side so shuffle/LDS/exp latencies overlap.
    short* os = xs;   // attention-out overlays q slices head-by-head
    const s8v z8 = {};
    s8v kf[2][4];     // A-frags: k[t_k = nt*16+l15][c]  (qd>=2 zeroed)
    #pragma unroll
    for (int hp = 0; hp < 2; ++hp) {
        const int h = wv + hp * 4;
        #pragma unroll
        for (int nt = 0; nt < 4; ++nt) {
            s8v kr = *(const s8v*)&ks[(nt * 16 + l15) * XSTR + h * 16 + (qd & 1) * 8];
            kf[hp][nt] = (qd < 2) ? kr : z8;
        }
    }
    #pragma unroll
    for (int mq = 0; mq < 4; ++mq) {
        // bias prefetch first (global; hides under the MFMAs below)
        f4v bf[2][4];
        #pragma unroll
        for (int hp = 0; hp < 2; ++hp) {
            const int h = wv + hp * 4;
            #pragma unroll
            for (int nt = 0; nt < 4; ++nt)
                bf[hp][nt] = *(const f4v*)&biasf[(size_t)(((h * 4 + mq) * 4 + nt) * 64 + lane) * 4];
        }
        s8v qf[2];
        #pragma unroll
        for (int hp = 0; hp < 2; ++hp) {
            const int h = wv + hp * 4;
            qf[hp] = *(const s8v*)&xs[(mq * 16 + l15) * XSTR + h * 16 + (qd & 1) * 8];
        }
        f4v sv[2][4];
        #pragma unroll
        for (int hp = 0; hp < 2; ++hp)
            #pragma unroll
            for (int nt = 0; nt < 4; ++nt) {
                f4v s = {0.f, 0.f, 0.f, 0.f};
                s = __builtin_amdgcn_mfma_f32_16x16x32_bf16(kf[hp][nt], qf[hp], s, 0, 0, 0);
                sv[hp][nt] = s + bf[hp][nt];   // scale+log2e folded into q/bias
            }
        // max (tree + 2 shfl), two chains
        float mx[2];
        #pragma unroll
        for (int hp = 0; hp < 2; ++hp) {
            f4v a01, a23, a;
            #pragma unroll
            for (int r = 0; r < 4; ++r) {
                a01[r] = fmaxf(sv[hp][0][r], sv[hp][1][r]);
                a23[r] = fmaxf(sv[hp][2][r], sv[hp][3][r]);
            }
            #pragma unroll
            for (int r = 0; r < 4; ++r) a[r] = fmaxf(a01[r], a23[r]);
            float m = fmaxf(fmaxf(a[0], a[1]), fmaxf(a[2], a[3]));
            m = fmaxf(m, __shfl_xor(m, 16, 64));
            m = fmaxf(m, __shfl_xor(m, 32, 64));
            mx[hp] = m;
        }
        // exp2 + tree-sum + 2 shfl, two chains
        float inv[2];
        #pragma unroll
        for (int hp = 0; hp < 2; ++hp) {
            #pragma unroll
            for (int nt = 0; nt < 4; ++nt)
                #pragma unroll
                for (int r = 0; r < 4; ++r)
                    sv[hp][nt][r] = exp2f(sv[hp][nt][r] - mx[hp]);
            f4v s01 = sv[hp][0] + sv[hp][1];
            f4v s23 = sv[hp][2] + sv[hp][3];
            f4v s4  = s01 + s23;
            float sm = (s4[0] + s4[1]) + (s4[2] + s4[3]);
            sm += __shfl_xor(sm, 16, 64);
            sm += __shfl_xor(sm, 32, 64);
            inv[hp] = 1.f / sm;
        }
        // normalized P -> per-(wave,hp) scratch; read back; PV; store O
        #pragma unroll
        for (int hp = 0; hp < 2; ++hp) {
            const int h = wv + hp * 4;
            short* pw = &vsc[(wv * 2 + hp) * 16 * VSTR];
            #pragma unroll
            for (int nt = 0; nt < 4; ++nt) {
                s4v pk;
                #pragma unroll
                for (int r = 0; r < 4; ++r) pk[r] = f2bf(sv[hp][nt][r] * inv[hp]);
                *(s4v*)&pw[l15 * VSTR + nt * 16 + qd * 4] = pk;
            }
            s8v pa0 = *(const s8v*)&pw[l15 * VSTR + qd * 8];
            s8v pa1 = *(const s8v*)&pw[l15 * VSTR + 32 + qd * 8];
            f4v O = {0.f, 0.f, 0.f, 0.f};
            O = __builtin_amdgcn_mfma_f32_16x16x32_bf16(pa0, vf[hp][0], O, 0, 0, 0);
            O = __builtin_amdgcn_mfma_f32_16x16x32_bf16(pa1, vf[hp][1], O, 0, 0, 0);
            #pragma unroll
            for (int r = 0; r < 4; ++r)
                os[(mq * 16 + qd * 4 + r) * XSTR + h * HD + l15] = f2bf(O[r]);
        }
    }

    // ---------- Stage 4: prefetch proj frags BEFORE the barrier ----------
    const s8v* wf = (const s8v*)wpk;
    s8v B[2][4];
    float pb2[2]; int o2[2];
    #pragma unroll
    for (int nt = 0; nt < 2; ++nt) {
        const int ob = 24 + wv * 2 + nt;
        o2[nt] = (wv * 2 + nt) * 16 + l15;
        pb2[nt] = proj_b[o2[nt]];
        #pragma unroll
        for (int kc = 0; kc < 4; ++kc) B[nt][kc] = wf[(ob * 4 + kc) * 64 + lane];
    }
    __syncthreads();
    {
        s8v A[4][4];
        #pragma unroll
        for (int mt = 0; mt < 4; ++mt)
            #pragma unroll
            for (int kc = 0; kc < 4; ++kc)
                A[mt][kc] = *(const s8v*)&xs[(mt * 16 + l15) * XSTR + kc * 32 + qd * 8];

        #pragma unroll
        for (int mt = 0; mt < 4; ++mt) {
            const int t0 = mt * 16 + qd * 4;
            const int pix = (h0 + (t0 >> 3)) * 256 + w0 + (t0 & 7);
            #pragma unroll
            for (int nt = 0; nt < 2; ++nt) {
                f4v acc = {0.f, 0.f, 0.f, 0.f};
                #pragma unroll
                for (int kc = 0; kc < 4; ++kc)
                    acc = __builtin_amdgcn_mfma_f32_16x16x32_bf16(A[mt][kc], B[nt][kc], acc, 0, 0, 0);
                float4 v = make_float4(acc[0] + pb2[nt], acc[1] + pb2[nt],
                                       acc[2] + pb2[nt], acc[3] + pb2[nt]);
                *(float4*)&out[((size_t)(b * CDIM + o2[nt])) * HW + pix] = v;
            }
        }
    }
}

extern "C" void kernel_launch(void* const* d_in, const int* in_sizes, int n_in,
                              void* d_out, int out_size, void* d_ws, size_t ws_size,
                              hipStream_t stream) {
    const float* x        = (const float*)d_in[0];
    const float* qkv_w    = (const float*)d_in[1];
    const float* qkv_b    = (const float*)d_in[2];
    const float* proj_w   = (const float*)d_in[3];
    const float* proj_b   = (const float*)d_in[4];
    const float* rel_bias = (const float*)d_in[5];
    const int*   rel_index= (const int*)d_in[6];
    float* out = (float*)d_out;

    short* wpk   = (short*)d_ws;                       // 32*4*64*8 shorts = 128 KB
    float* biasf = (float*)((char*)d_ws + 131072);     // 8192 float4 = 128 KB

    pack_w_kernel<<<32, 256, 0, stream>>>(qkv_w, proj_w, wpk);
    pack_b_kernel<<<32, 256, 0, stream>>>(rel_bias, rel_index, biasf);
    winattn_kernel<<<2048, 256, 0, stream>>>(x, qkv_b, proj_b, wpk, biasf, out);
}